// Round 4
// baseline (416.239 us; speedup 1.0000x reference)
//
#include <hip/hip_runtime.h>
#include <hip/hip_bf16.h>
#include <hip/hip_cooperative_groups.h>

namespace cg = cooperative_groups;

#define BB 16
#define CC 256
#define HWN 3136
#define NCI 32
#define NPP 784   // 28*28
#define GRID 256

typedef __attribute__((ext_vector_type(8))) short short8;
typedef __attribute__((ext_vector_type(4))) float floatx4;

__device__ __forceinline__ unsigned short f2bf(float f) {
    union { __hip_bfloat16 h; unsigned short u; } cv;
    cv.h = __float2bfloat16(f);
    return cv.u;
}
__device__ __forceinline__ float bf2f(unsigned short u) {
    return __uint_as_float(((unsigned)u) << 16);
}

__device__ __forceinline__ void stage_Tt(unsigned short* Tt, const unsigned short* th,
                                         int b, int hw0, int tid) {
    int p2 = tid & 15, hwq = tid >> 4;
    int c0 = 2 * p2;
    const unsigned short* tb = th + (size_t)(b * NCI) * HWN + hw0 + hwq * 4;
    ushort4 v0 = *(const ushort4*)(tb + (size_t)c0 * HWN);
    ushort4 v1 = *(const ushort4*)(tb + (size_t)(c0 + 1) * HWN);
    unsigned int* tw = (unsigned int*)Tt;
    tw[(hwq * 4 + 0) * 20 + p2] = (unsigned)v0.x | ((unsigned)v1.x << 16);
    tw[(hwq * 4 + 1) * 20 + p2] = (unsigned)v0.y | ((unsigned)v1.y << 16);
    tw[(hwq * 4 + 2) * 20 + p2] = (unsigned)v0.z | ((unsigned)v1.z << 16);
    tw[(hwq * 4 + 3) * 20 + p2] = (unsigned)v0.w | ((unsigned)v1.w << 16);
}

// ============================ fused cooperative kernel (GRID=256, 1 block/CU) ============================
__global__ __launch_bounds__(256, 1) void k_fused(
    const float* __restrict__ x,
    const float* __restrict__ bn1g, const float* __restrict__ bn1b,
    const float* __restrict__ w_g, const float* __restrict__ b_g,
    const float* __restrict__ w_t, const float* __restrict__ b_t,
    const float* __restrict__ w_p, const float* __restrict__ b_p,
    const float* __restrict__ bn2g, const float* __restrict__ bn2b,
    const float* __restrict__ w_z, const float* __restrict__ b_z,
    float* __restrict__ out,
    unsigned short* __restrict__ wcat, unsigned short* __restrict__ wzb,
    unsigned short* __restrict__ th, unsigned short* __restrict__ pool,
    unsigned short* __restrict__ Sg,
    float* __restrict__ bn1part, float* __restrict__ zacc,
    float* __restrict__ bn2acc, float* __restrict__ T1g, float* __restrict__ Gg)
{
    cg::grid_group gr = cg::this_grid();
    int blk = blockIdx.x;
    int tid = threadIdx.x;
    int wv = tid >> 6, ln = tid & 63;
    int col = ln & 15, quad = ln >> 4;

    __shared__ unsigned short regA[18432];   // 36864 B
    __shared__ unsigned short TSm[5120];     // 10240 B
    __shared__ float abm[512];
    __shared__ float bias_s[128];

    // ---------------- phase 0 ----------------
    if (blk < 128) {
        int o = blk, c = tid;
        const float* src = (o < 32) ? (w_t + o * CC)
                          : (o < 64) ? (w_p + (o - 32) * CC)
                                     : (w_g + (o - 64) * CC);
        wcat[o * CC + c] = f2bf(src[c]);
        int r = o * 2 + (c >> 7), kk = c & 127;
        if (kk < 72)
            wzb[r * 72 + kk] = (kk < 64) ? f2bf(w_z[r * 64 + kk]) : (unsigned short)0;
    }
    for (int i = blk * 256 + tid; i < 17024; i += GRID * 256) zacc[i] = 0.f;
    for (int i = blk * 256 + tid; i < 24576; i += GRID * 256) {
        int o = i >> 8, b = (i >> 4) & 15, kk = i & 15;
        pool[((size_t)(b * 96 + o)) * 800 + 784 + kk] = 0;
    }
    {   // BN1 per-plane stats: one wave per (b,c) plane, non-atomic
        int gw = blk * 4 + wv;
        for (int p = gw; p < 4096; p += 4 * GRID) {
            const float4* pp = (const float4*)(x + (size_t)p * HWN);
            float s = 0.f, q = 0.f;
            for (int i = ln; i < 784; i += 64) {
                float4 v = pp[i];
                s += v.x + v.y + v.z + v.w;
                q += v.x * v.x + v.y * v.y + v.z * v.z + v.w * v.w;
            }
            #pragma unroll
            for (int off = 32; off > 0; off >>= 1) {
                s += __shfl_down(s, off);
                q += __shfl_down(q, off);
            }
            if (ln == 0) { bn1part[p] = s; bn1part[4096 + p] = q; }
        }
    }
    __threadfence();
    gr.sync();
    __threadfence();

    // ---------------- phase 1: conv1, 448 tiles over 256 blocks ----------------
    {
        unsigned short* As = regA;
        unsigned short* Bs = regA + 4096;
        float* ab_s = abm;

        {   // fold BN1 finalize from per-batch partials
            const float inv = 1.0f / (BB * HWN);
            float s = 0.f, q = 0.f;
            #pragma unroll
            for (int b2 = 0; b2 < BB; ++b2) {
                s += bn1part[b2 * 256 + tid];
                q += bn1part[4096 + b2 * 256 + tid];
            }
            float mean = s * inv;
            float var  = q * inv - mean * mean;
            float a = bn1g[tid] * rsqrtf(var + 1e-5f);
            ab_s[tid] = a;
            ab_s[CC + tid] = bn1b[tid] - mean * a;
        }
        if (tid < 128) {
            int o = tid;
            bias_s[o] = (o < 32) ? b_t[o] : (o < 64) ? b_p[o - 32] : b_g[o - 64];
        }
        __syncthreads();

        for (int t = blk; t < 448; t += GRID) {
            int b  = t / 28;
            int bx = t % 28;
            int hw0 = bx * 112;

            floatx4 acc[2][7];
            #pragma unroll
            for (int mt = 0; mt < 2; ++mt)
                for (int nt = 0; nt < 7; ++nt)
                    acc[mt][nt] = (floatx4){0.f, 0.f, 0.f, 0.f};

            int p   = tid & 15;    // c-pair index
            int hwq = tid >> 4;    // base hw-quad (0..15)
            const float* xb = x + (size_t)(b * CC) * HWN + hw0;
            bool q1 = (hwq + 16) < 28;

            float4 pv0[2], pv1[2];
            {   // prefetch k0=0
                int c0 = 2 * p;
                pv0[0] = *(const float4*)(xb + (size_t)c0 * HWN + hwq * 4);
                pv1[0] = *(const float4*)(xb + (size_t)(c0 + 1) * HWN + hwq * 4);
                if (q1) {
                    pv0[1] = *(const float4*)(xb + (size_t)c0 * HWN + (hwq + 16) * 4);
                    pv1[1] = *(const float4*)(xb + (size_t)(c0 + 1) * HWN + (hwq + 16) * 4);
                }
            }

            for (int k0 = 0; k0 < CC; k0 += 32) {
                #pragma unroll
                for (int i = 0; i < 2; ++i) {   // stage A (weights) via DMA
                    int row = wv * 32 + i * 16 + (ln >> 2);
                    int q   = ln & 3;
                    const unsigned short* gp = wcat + row * CC + k0 + q * 8;
                    __builtin_amdgcn_global_load_lds(
                        (const __attribute__((address_space(1))) unsigned int*)gp,
                        (__attribute__((address_space(3))) unsigned int*)&As[(wv * 2 + i) * 512],
                        16, 0, 0);
                }
                {   // stage B from prefetched regs (BN1+ReLU+bf16)
                    int c0 = k0 + 2 * p;
                    float a0 = ab_s[c0],     d0 = ab_s[CC + c0];
                    float a1 = ab_s[c0 + 1], d1 = ab_s[CC + c0 + 1];
                    unsigned int* bw = (unsigned int*)Bs;
                    #pragma unroll
                    for (int tt = 0; tt < 2; ++tt) {
                        if (tt == 0 || q1) {
                            int qi = hwq + 16 * tt;
                            float4 v0 = pv0[tt], v1 = pv1[tt];
                            float r0[4] = { fmaxf(fmaf(a0, v0.x, d0), 0.f), fmaxf(fmaf(a0, v0.y, d0), 0.f),
                                            fmaxf(fmaf(a0, v0.z, d0), 0.f), fmaxf(fmaf(a0, v0.w, d0), 0.f) };
                            float r1[4] = { fmaxf(fmaf(a1, v1.x, d1), 0.f), fmaxf(fmaf(a1, v1.y, d1), 0.f),
                                            fmaxf(fmaf(a1, v1.z, d1), 0.f), fmaxf(fmaf(a1, v1.w, d1), 0.f) };
                            #pragma unroll
                            for (int i = 0; i < 4; ++i) {
                                unsigned int w = (unsigned int)f2bf(r0[i]) | ((unsigned int)f2bf(r1[i]) << 16);
                                bw[(qi * 4 + i) * 16 + p] = w;
                            }
                        }
                    }
                }
                __syncthreads();

                if (k0 + 32 < CC) {   // prefetch next k-step's x under the MFMAs
                    int c0 = k0 + 32 + 2 * p;
                    pv0[0] = *(const float4*)(xb + (size_t)c0 * HWN + hwq * 4);
                    pv1[0] = *(const float4*)(xb + (size_t)(c0 + 1) * HWN + hwq * 4);
                    if (q1) {
                        pv0[1] = *(const float4*)(xb + (size_t)c0 * HWN + (hwq + 16) * 4);
                        pv1[1] = *(const float4*)(xb + (size_t)(c0 + 1) * HWN + (hwq + 16) * 4);
                    }
                }

                short8 af0 = *(const short8*)&As[(wv * 32 +      col) * 32 + quad * 8];
                short8 af1 = *(const short8*)&As[(wv * 32 + 16 + col) * 32 + quad * 8];
                #pragma unroll
                for (int nt = 0; nt < 7; ++nt) {
                    short8 bf = *(const short8*)&Bs[(nt * 16 + col) * 32 + quad * 8];
                    acc[0][nt] = __builtin_amdgcn_mfma_f32_16x16x32_bf16(af0, bf, acc[0][nt], 0, 0, 0);
                    acc[1][nt] = __builtin_amdgcn_mfma_f32_16x16x32_bf16(af1, bf, acc[1][nt], 0, 0, 0);
                }
                __syncthreads();
            }

            // ---- stage C (with bias) to LDS ----
            unsigned short* Ct = regA;    // [128][120]
            #pragma unroll
            for (int mt = 0; mt < 2; ++mt) {
                int obase = wv * 32 + mt * 16 + quad * 4;
                #pragma unroll
                for (int r = 0; r < 4; ++r) {
                    float bias = bias_s[obase + r];
                    #pragma unroll
                    for (int nt = 0; nt < 7; ++nt)
                        Ct[(obase + r) * 120 + nt * 16 + col] = f2bf(acc[mt][nt][r] + bias);
                }
            }
            __syncthreads();

            // ---- theta (ch 0..31): full-res vectorized store ----
            #pragma unroll
            for (int i = 0; i < 4; ++i) {
                int e = tid + i * 256;
                if (e < 896) {
                    int ch = e / 28, c4 = e - ch * 28;
                    ushort4 v = *(const ushort4*)&Ct[ch * 120 + c4 * 4];
                    *(ushort4*)&th[((size_t)(b * NCI + ch)) * HWN + hw0 + c4 * 4] = v;
                }
            }
            // ---- T1: per-batch theta row sums ----
            {
                int row = tid >> 3, seg = tid & 7;
                float s = 0.f;
                #pragma unroll
                for (int j = 0; j < 14; ++j) s += bf2f(Ct[row * 120 + seg * 14 + j]);
                s += __shfl_down(s, 4);
                s += __shfl_down(s, 2);
                s += __shfl_down(s, 1);
                if (seg == 0) atomicAdd(&T1g[b * NCI + row], s);
            }
            // ---- Gram: theta.theta^T over this tile's 112 hw ----
            {
                int m = wv >> 1, n = wv & 1;
                floatx4 g = (floatx4){0.f, 0.f, 0.f, 0.f};
                short8 z8 = (short8){0, 0, 0, 0, 0, 0, 0, 0};
                #pragma unroll
                for (int ks = 0; ks < 4; ++ks) {
                    short8 ga, gb;
                    if (ks < 3 || quad < 2) {
                        ga = *(const short8*)&Ct[(m * 16 + col) * 120 + ks * 32 + quad * 8];
                        gb = *(const short8*)&Ct[(n * 16 + col) * 120 + ks * 32 + quad * 8];
                    } else {
                        ga = z8; gb = z8;
                    }
                    g = __builtin_amdgcn_mfma_f32_16x16x32_bf16(ga, gb, g, 0, 0, 0);
                }
                float* ggp = Gg + b * 1024 + (m * 16 + quad * 4) * 32 + n * 16 + col;
                #pragma unroll
                for (int r = 0; r < 4; ++r) atomicAdd(&ggp[r * 32], g[r]);
            }
            // ---- phi/g (ch 32..127): 2x2 maxpool ----
            #pragma unroll
            for (int i = 0; i < 11; ++i) {
                int e = tid + i * 256;
                if (e < 2688) {
                    int ch = e / 28, m = e - ch * 28;
                    const unsigned short* r0p = &Ct[(32 + ch) * 120 + 2 * m];
                    float v = fmaxf(fmaxf(bf2f(r0p[0]), bf2f(r0p[1])),
                                    fmaxf(bf2f(r0p[56]), bf2f(r0p[57])));
                    pool[((size_t)(b * 96 + ch)) * 800 + bx * 28 + m] = f2bf(v);
                }
            }
            __syncthreads();   // Ct readers done before next tile's As DMA
        }
    }
    __threadfence();
    gr.sync();
    __threadfence();

    // ---------------- phase 2: sgemm (blk<16) + Wl/Tt prestage (all) ----------------
    if (blk < 16) {
        int b = blk;
        float* Sred = (float*)regA;          // [4][2048]
        float* Gred = (float*)TSm;           // [1024]
        float* T1s  = abm;                   // [32]
        float* shs  = abm + 64;              // [64]
        float* shq  = abm + 128;             // [64]
        if (tid < 64) { shs[tid] = 0.f; shq[tid] = 0.f; }
        if (tid < 32) T1s[tid] = T1g[b * NCI + tid];
        for (int idx = tid; idx < 1024; idx += 256) Gred[idx] = Gg[b * 1024 + idx];

        const unsigned short* gbase = pool + ((size_t)(b * 96 + 32)) * 800;
        const unsigned short* pbase = pool + ((size_t)(b * 96)) * 800;
        floatx4 acc[4][2];
        #pragma unroll
        for (int mt = 0; mt < 4; ++mt)
            for (int nt = 0; nt < 2; ++nt)
                acc[mt][nt] = (floatx4){0.f, 0.f, 0.f, 0.f};
        for (int ks = wv; ks < 25; ks += 4) {
            int k0 = ks * 32;
            short8 af[4], bfr[2];
            #pragma unroll
            for (int mt = 0; mt < 4; ++mt)
                af[mt] = *(const short8*)&gbase[(mt * 16 + col) * 800 + k0 + quad * 8];
            #pragma unroll
            for (int nt = 0; nt < 2; ++nt)
                bfr[nt] = *(const short8*)&pbase[(nt * 16 + col) * 800 + k0 + quad * 8];
            #pragma unroll
            for (int mt = 0; mt < 4; ++mt)
                #pragma unroll
                for (int nt = 0; nt < 2; ++nt)
                    acc[mt][nt] = __builtin_amdgcn_mfma_f32_16x16x32_bf16(af[mt], bfr[nt], acc[mt][nt], 0, 0, 0);
        }
        #pragma unroll
        for (int mt = 0; mt < 4; ++mt)
            for (int nt = 0; nt < 2; ++nt)
                for (int r = 0; r < 4; ++r)
                    Sred[wv * 2048 + (mt * 16 + quad * 4 + r) * 32 + nt * 16 + col] = acc[mt][nt][r];
        __syncthreads();

        for (int idx = tid; idx < 2048; idx += 256) {
            float s = Sred[idx] + Sred[2048 + idx] + Sred[4096 + idx] + Sred[6144 + idx];
            int cgi = idx >> 5, ci = idx & 31;
            unsigned short h = f2bf(s * (1.0f / NPP));
            Sg[(size_t)b * 2560 + cgi * 40 + ci] = h;
            Sred[idx] = bf2f(h);
        }
        __syncthreads();

        {   // BN2 stats: sum = S.T1, sumsq = s^T G s
            int cgi = tid & 63, part = tid >> 6;   // 4 parts x 8 ci
            float sum = 0.f, sq = 0.f;
            #pragma unroll
            for (int i = 0; i < 8; ++i) {
                int ci = part * 8 + i;
                float sv = Sred[cgi * 32 + ci];
                sum += sv * T1s[ci];
                float t2 = 0.f;
                #pragma unroll
                for (int cj = 0; cj < 32; ++cj)
                    t2 += Gred[ci * 32 + cj] * Sred[cgi * 32 + cj];
                sq += sv * t2;
            }
            atomicAdd(&shs[cgi], sum);
            atomicAdd(&shq[cgi], sq);
        }
        __syncthreads();
        if (tid < 64) {
            atomicAdd(&bn2acc[tid], shs[tid]);
            atomicAdd(&bn2acc[64 + tid], shq[tid]);
        }
        __syncthreads();
    }
    // all blocks: Wl DMA + first-tile Tt prestage — fills sgemm idle time
    for (int j = wv; j < 36; j += 4) {
        const unsigned short* gp = wzb + j * 512 + ln * 8;
        __builtin_amdgcn_global_load_lds(
            (const __attribute__((address_space(1))) unsigned int*)gp,
            (__attribute__((address_space(3))) unsigned int*)&regA[j * 512],
            16, 0, 0);
    }
    stage_Tt(TSm, th, blk / 49, (blk % 49) * 64, tid);
    __threadfence();
    gr.sync();
    __threadfence();

    // ---------------- phase 3: convz (784 tiles over 256 blocks) ----------------
    {
        unsigned short* Wl = regA;
        unsigned short* Tt = TSm;
        unsigned short* St = TSm + 2560;
        unsigned short* Yt = TSm;

        if (tid < 64) {   // BN2 finalize
            const float inv = 1.0f / (BB * HWN);
            float mean = bn2acc[tid] * inv;
            float var  = bn2acc[64 + tid] * inv - mean * mean;
            float a = bn2g[tid] * rsqrtf(var + 1e-5f);
            abm[tid] = a;
            abm[64 + tid] = bn2b[tid] - mean * a;
        }

        for (int t = blk; t < 784; t += GRID) {
            int b = t / 49, hw0 = (t % 49) * 64;
            if (t != blk) {
                __syncthreads();          // prior Yt reads complete
                stage_Tt(Tt, th, b, hw0, tid);
            }
            {   // stage St (bf16 S, pre-scaled)
                const unsigned int* sgw = (const unsigned int*)(Sg + (size_t)b * 2560);
                unsigned int* stw = (unsigned int*)St;
                for (int i = tid; i < 1280; i += 256) stw[i] = sgw[i];
            }
            __syncthreads();

            // recompute y tile: y[hw][cg]
            short8 afy = *(const short8*)&Tt[(wv * 16 + col) * 40 + quad * 8];
            floatx4 yacc[4];
            #pragma unroll
            for (int nt = 0; nt < 4; ++nt) {
                short8 bf = *(const short8*)&St[(nt * 16 + col) * 40 + quad * 8];
                floatx4 z = (floatx4){0.f, 0.f, 0.f, 0.f};
                yacc[nt] = __builtin_amdgcn_mfma_f32_16x16x32_bf16(afy, bf, z, 0, 0, 0);
            }
            __syncthreads();   // Tt/St reads done before Yt overlay

            #pragma unroll
            for (int nt = 0; nt < 4; ++nt) {
                int cgi = nt * 16 + col;
                float a = abm[cgi], d = abm[64 + cgi];
                #pragma unroll
                for (int r = 0; r < 4; ++r) {
                    int hwl = wv * 16 + quad * 4 + r;
                    Yt[hwl * 72 + cgi] = f2bf(fmaxf(fmaf(a, yacc[nt][r], d), 0.f));
                }
            }
            __syncthreads();

            floatx4 acc[16];
            #pragma unroll
            for (int nt = 0; nt < 16; ++nt) acc[nt] = (floatx4){0.f, 0.f, 0.f, 0.f};
            #pragma unroll
            for (int kk = 0; kk < 2; ++kk) {
                short8 afm = *(const short8*)&Yt[(wv * 16 + col) * 72 + kk * 32 + quad * 8];
                #pragma unroll
                for (int nt = 0; nt < 16; ++nt) {
                    short8 bf = *(const short8*)&Wl[(nt * 16 + col) * 72 + kk * 32 + quad * 8];
                    acc[nt] = __builtin_amdgcn_mfma_f32_16x16x32_bf16(afm, bf, acc[nt], 0, 0, 0);
                }
            }
            #pragma unroll
            for (int nt = 0; nt < 16; ++nt) {
                int co = nt * 16 + col;
                size_t base = ((size_t)(b * CC + co)) * HWN + hw0 + wv * 16 + quad * 4;
                float4 xv = *(const float4*)&x[base];
                float bz = b_z[co];
                float4 r = make_float4(acc[nt][0] + bz + xv.x, acc[nt][1] + bz + xv.y,
                                       acc[nt][2] + bz + xv.z, acc[nt][3] + bz + xv.w);
                *(float4*)&out[base] = r;
            }
        }
    }
}

// ============================ fallback: verbatim R1 pipeline (known-passing) ============================
__global__ __launch_bounds__(256) void kf_head(const float* __restrict__ x,
                                               const float* __restrict__ w_t,
                                               const float* __restrict__ w_p,
                                               const float* __restrict__ w_g,
                                               const float* __restrict__ w_z,
                                               unsigned short* __restrict__ wcat,
                                               unsigned short* __restrict__ wzb,
                                               unsigned short* __restrict__ pool,
                                               float* __restrict__ zacc,
                                               float* __restrict__ bn1part) {
    int blk = blockIdx.x;
    int c = threadIdx.x;
    if (blk < 128) {
        int o = blk;
        const float* src = (o < 32) ? (w_t + o * CC)
                          : (o < 64) ? (w_p + (o - 32) * CC)
                                     : (w_g + (o - 64) * CC);
        wcat[o * CC + c] = f2bf(src[c]);
        {
            int r = o * 2 + (c >> 7);
            int kk = c & 127;
            if (kk < 72)
                wzb[r * 72 + kk] = (kk < 64) ? f2bf(w_z[r * 64 + kk]) : (unsigned short)0;
        }
        if (o < 96) {
            int b = c >> 4, kk = c & 15;
            pool[((size_t)(b * 96 + o)) * 800 + 784 + kk] = 0;
        }
        int idx = o * 256 + c;
        if (idx < 17024) zacc[idx] = 0.f;
        return;
    }
    int bc = blk - 128;
    const float4* p = (const float4*)(x + (size_t)bc * HWN);
    int tid = c;
    float s = 0.f, q = 0.f;
    for (int i = tid; i < 784; i += 256) {
        float4 v = p[i];
        s += v.x + v.y + v.z + v.w;
        q += v.x * v.x + v.y * v.y + v.z * v.z + v.w * v.w;
    }
    #pragma unroll
    for (int off = 32; off > 0; off >>= 1) {
        s += __shfl_down(s, off);
        q += __shfl_down(q, off);
    }
    __shared__ float sh[16];
    int wid = tid >> 6, lane = tid & 63;
    if (lane == 0) { sh[wid] = s; sh[8 + wid] = q; }
    __syncthreads();
    if (tid == 0) bn1part[bc]        = sh[0] + sh[1] + sh[2] + sh[3];
    if (tid == 1) bn1part[4096 + bc] = sh[8] + sh[9] + sh[10] + sh[11];
}

__global__ __launch_bounds__(256) void kf_conv1(const float* __restrict__ x,
                                                const unsigned short* __restrict__ wcat,
                                                const float* __restrict__ bn1part,
                                                const float* __restrict__ gamma,
                                                const float* __restrict__ beta,
                                                const float* __restrict__ b_g,
                                                const float* __restrict__ b_t,
                                                const float* __restrict__ b_p,
                                                unsigned short* __restrict__ th,
                                                unsigned short* __restrict__ pool,
                                                float* __restrict__ T1g,
                                                float* __restrict__ Gg) {
    int b  = blockIdx.y;
    int bx = blockIdx.x;
    int hw0 = bx * 112;
    int tid = threadIdx.x;
    int wv = tid >> 6, ln = tid & 63;
    int col = ln & 15, quad = ln >> 4;

    __shared__ unsigned short smem[128 * 120];
    unsigned short* As = smem;
    unsigned short* Bs = smem + 4096;
    __shared__ float ab_s[512];
    __shared__ float bias_s[128];

    {
        const float inv = 1.0f / (BB * HWN);
        float s = 0.f, q = 0.f;
        #pragma unroll
        for (int b2 = 0; b2 < BB; ++b2) {
            s += bn1part[b2 * 256 + tid];
            q += bn1part[4096 + b2 * 256 + tid];
        }
        float mean = s * inv;
        float var  = q * inv - mean * mean;
        float a = gamma[tid] * rsqrtf(var + 1e-5f);
        ab_s[tid] = a;
        ab_s[CC + tid] = beta[tid] - mean * a;
    }
    if (tid < 128) {
        int o = tid;
        bias_s[o] = (o < 32) ? b_t[o] : (o < 64) ? b_p[o - 32] : b_g[o - 64];
    }
    __syncthreads();

    floatx4 acc[2][7];
    #pragma unroll
    for (int mt = 0; mt < 2; ++mt)
        for (int nt = 0; nt < 7; ++nt)
            acc[mt][nt] = (floatx4){0.f, 0.f, 0.f, 0.f};

    int p   = tid & 15;
    int hwq = tid >> 4;
    const float* xb = x + (size_t)(b * CC) * HWN + hw0;
    bool q1 = (hwq + 16) < 28;

    float4 pv0[2], pv1[2];
    {
        int c0 = 2 * p;
        pv0[0] = *(const float4*)(xb + (size_t)c0 * HWN + hwq * 4);
        pv1[0] = *(const float4*)(xb + (size_t)(c0 + 1) * HWN + hwq * 4);
        if (q1) {
            pv0[1] = *(const float4*)(xb + (size_t)c0 * HWN + (hwq + 16) * 4);
            pv1[1] = *(const float4*)(xb + (size_t)(c0 + 1) * HWN + (hwq + 16) * 4);
        }
    }

    for (int k0 = 0; k0 < CC; k0 += 32) {
        #pragma unroll
        for (int i = 0; i < 2; ++i) {
            int row = wv * 32 + i * 16 + (ln >> 2);
            int q   = ln & 3;
            const unsigned short* gp = wcat + row * CC + k0 + q * 8;
            __builtin_amdgcn_global_load_lds(
                (const __attribute__((address_space(1))) unsigned int*)gp,
                (__attribute__((address_space(3))) unsigned int*)&As[(wv * 2 + i) * 512],
                16, 0, 0);
        }
        {
            int c0 = k0 + 2 * p;
            float a0 = ab_s[c0],     d0 = ab_s[CC + c0];
            float a1 = ab_s[c0 + 1], d1 = ab_s[CC + c0 + 1];
            unsigned int* bw = (unsigned int*)Bs;
            #pragma unroll
            for (int t = 0; t < 2; ++t) {
                if (t == 0 || q1) {
                    int qi = hwq + 16 * t;
                    float4 v0 = pv0[t], v1 = pv1[t];
                    float r0[4] = { fmaxf(fmaf(a0, v0.x, d0), 0.f), fmaxf(fmaf(a0, v0.y, d0), 0.f),
                                    fmaxf(fmaf(a0, v0.z, d0), 0.f), fmaxf(fmaf(a0, v0.w, d0), 0.f) };
                    float r1[4] = { fmaxf(fmaf(a1, v1.x, d1), 0.f), fmaxf(fmaf(a1, v1.y, d1), 0.f),
                                    fmaxf(fmaf(a1, v1.z, d1), 0.f), fmaxf(fmaf(a1, v1.w, d1), 0.f) };
                    #pragma unroll
                    for (int i = 0; i < 4; ++i) {
                        unsigned int w = (unsigned int)f2bf(r0[i]) | ((unsigned int)f2bf(r1[i]) << 16);
                        bw[(qi * 4 + i) * 16 + p] = w;
                    }
                }
            }
        }
        __syncthreads();

        if (k0 + 32 < CC) {
            int c0 = k0 + 32 + 2 * p;
            pv0[0] = *(const float4*)(xb + (size_t)c0 * HWN + hwq * 4);
            pv1[0] = *(const float4*)(xb + (size_t)(c0 + 1) * HWN + hwq * 4);
            if (q1) {
                pv0[1] = *(const float4*)(xb + (size_t)c0 * HWN + (hwq + 16) * 4);
                pv1[1] = *(const float4*)(xb + (size_t)(c0 + 1) * HWN + (hwq + 16) * 4);
            }
        }

        short8 af0 = *(const short8*)&As[(wv * 32 +      col) * 32 + quad * 8];
        short8 af1 = *(const short8*)&As[(wv * 32 + 16 + col) * 32 + quad * 8];
        #pragma unroll
        for (int nt = 0; nt < 7; ++nt) {
            short8 bf = *(const short8*)&Bs[(nt * 16 + col) * 32 + quad * 8];
            acc[0][nt] = __builtin_amdgcn_mfma_f32_16x16x32_bf16(af0, bf, acc[0][nt], 0, 0, 0);
            acc[1][nt] = __builtin_amdgcn_mfma_f32_16x16x32_bf16(af1, bf, acc[1][nt], 0, 0, 0);
        }
        __syncthreads();
    }

    unsigned short* Ct = smem;
    #pragma unroll
    for (int mt = 0; mt < 2; ++mt) {
        int obase = wv * 32 + mt * 16 + quad * 4;
        #pragma unroll
        for (int r = 0; r < 4; ++r) {
            float bias = bias_s[obase + r];
            #pragma unroll
            for (int nt = 0; nt < 7; ++nt)
                Ct[(obase + r) * 120 + nt * 16 + col] = f2bf(acc[mt][nt][r] + bias);
        }
    }
    __syncthreads();

    #pragma unroll
    for (int i = 0; i < 4; ++i) {
        int e = tid + i * 256;
        if (e < 896) {
            int ch = e / 28, c4 = e - ch * 28;
            ushort4 v = *(const ushort4*)&Ct[ch * 120 + c4 * 4];
            *(ushort4*)&th[((size_t)(b * NCI + ch)) * HWN + hw0 + c4 * 4] = v;
        }
    }
    {
        int row = tid >> 3, seg = tid & 7;
        float s = 0.f;
        #pragma unroll
        for (int j = 0; j < 14; ++j) s += bf2f(Ct[row * 120 + seg * 14 + j]);
        s += __shfl_down(s, 4);
        s += __shfl_down(s, 2);
        s += __shfl_down(s, 1);
        if (seg == 0) atomicAdd(&T1g[b * NCI + row], s);
    }
    {
        int m = wv >> 1, n = wv & 1;
        floatx4 g = (floatx4){0.f, 0.f, 0.f, 0.f};
        short8 z8 = (short8){0, 0, 0, 0, 0, 0, 0, 0};
        #pragma unroll
        for (int ks = 0; ks < 4; ++ks) {
            short8 ga, gb;
            if (ks < 3 || quad < 2) {
                ga = *(const short8*)&Ct[(m * 16 + col) * 120 + ks * 32 + quad * 8];
                gb = *(const short8*)&Ct[(n * 16 + col) * 120 + ks * 32 + quad * 8];
            } else {
                ga = z8; gb = z8;
            }
            g = __builtin_amdgcn_mfma_f32_16x16x32_bf16(ga, gb, g, 0, 0, 0);
        }
        float* ggp = Gg + b * 1024 + (m * 16 + quad * 4) * 32 + n * 16 + col;
        #pragma unroll
        for (int r = 0; r < 4; ++r) atomicAdd(&ggp[r * 32], g[r]);
    }
    #pragma unroll
    for (int i = 0; i < 11; ++i) {
        int e = tid + i * 256;
        if (e < 2688) {
            int ch = e / 28, m = e - ch * 28;
            const unsigned short* r0p = &Ct[(32 + ch) * 120 + 2 * m];
            float v = fmaxf(fmaxf(bf2f(r0p[0]), bf2f(r0p[1])),
                            fmaxf(bf2f(r0p[56]), bf2f(r0p[57])));
            pool[((size_t)(b * 96 + ch)) * 800 + bx * 28 + m] = f2bf(v);
        }
    }
}

__global__ __launch_bounds__(512) void kf_sgemm(const unsigned short* __restrict__ pool,
                                                const float* __restrict__ T1g,
                                                const float* __restrict__ Gg,
                                                unsigned short* __restrict__ Sg,
                                                float* __restrict__ bn2acc) {
    int b = blockIdx.x;
    int tid = threadIdx.x;
    int wv = tid >> 6, ln = tid & 63;
    int col = ln & 15, quad = ln >> 4;
    __shared__ float Sred[8 * 2048];
    __shared__ float Gred[1024];
    __shared__ float T1s[32];
    __shared__ float shs[64], shq[64];

    if (tid < 64) { shs[tid] = 0.f; shq[tid] = 0.f; }
    if (tid < 32) T1s[tid] = T1g[b * NCI + tid];
    for (int idx = tid; idx < 1024; idx += 512) Gred[idx] = Gg[b * 1024 + idx];

    const unsigned short* gbase = pool + ((size_t)(b * 96 + 32)) * 800;
    const unsigned short* pbase = pool + ((size_t)(b * 96)) * 800;
    floatx4 acc[4][2];
    #pragma unroll
    for (int mt = 0; mt < 4; ++mt)
        for (int nt = 0; nt < 2; ++nt)
            acc[mt][nt] = (floatx4){0.f, 0.f, 0.f, 0.f};
    for (int s = wv; s < 25; s += 8) {
        int k0 = s * 32;
        short8 af[4], bfr[2];
        #pragma unroll
        for (int mt = 0; mt < 4; ++mt)
            af[mt] = *(const short8*)&gbase[(mt * 16 + col) * 800 + k0 + quad * 8];
        #pragma unroll
        for (int nt = 0; nt < 2; ++nt)
            bfr[nt] = *(const short8*)&pbase[(nt * 16 + col) * 800 + k0 + quad * 8];
        #pragma unroll
        for (int mt = 0; mt < 4; ++mt)
            #pragma unroll
            for (int nt = 0; nt < 2; ++nt)
                acc[mt][nt] = __builtin_amdgcn_mfma_f32_16x16x32_bf16(af[mt], bfr[nt], acc[mt][nt], 0, 0, 0);
    }
    #pragma unroll
    for (int mt = 0; mt < 4; ++mt)
        for (int nt = 0; nt < 2; ++nt)
            for (int r = 0; r < 4; ++r)
                Sred[wv * 2048 + (mt * 16 + quad * 4 + r) * 32 + nt * 16 + col] = acc[mt][nt][r];
    __syncthreads();

    for (int idx = tid; idx < 2048; idx += 512) {
        float s = 0.f;
        #pragma unroll
        for (int w = 0; w < 8; ++w) s += Sred[w * 2048 + idx];
        int cg = idx >> 5, ci = idx & 31;
        unsigned short h = f2bf(s * (1.0f / NPP));
        Sg[(size_t)b * 2560 + cg * 40 + ci] = h;
        Sred[idx] = bf2f(h);
    }
    __syncthreads();

    {
        int cg = tid & 63, part = tid >> 6;
        float sum = 0.f, sq = 0.f;
        #pragma unroll
        for (int i = 0; i < 4; ++i) {
            int ci = part * 4 + i;
            float sv = Sred[cg * 32 + ci];
            sum += sv * T1s[ci];
            float t = 0.f;
            #pragma unroll
            for (int cj = 0; cj < 32; ++cj)
                t += Gred[ci * 32 + cj] * Sred[cg * 32 + cj];
            sq += sv * t;
        }
        atomicAdd(&shs[cg], sum);
        atomicAdd(&shq[cg], sq);
    }
    __syncthreads();
    if (tid < 64) {
        atomicAdd(&bn2acc[tid], shs[tid]);
        atomicAdd(&bn2acc[64 + tid], shq[tid]);
    }
}

__global__ __launch_bounds__(256) void kf_convz(const unsigned short* __restrict__ th,
                                                const unsigned short* __restrict__ Sg,
                                                const unsigned short* __restrict__ wzb,
                                                const float* __restrict__ bn2acc,
                                                const float* __restrict__ gamma,
                                                const float* __restrict__ beta,
                                                const float* __restrict__ b_z,
                                                const float* __restrict__ x,
                                                float* __restrict__ out) {
    int b = blockIdx.y;
    int hw0 = blockIdx.x * 64;
    int tid = threadIdx.x;
    int wv = tid >> 6, ln = tid & 63;
    int col = ln & 15, quad = ln >> 4;

    __shared__ unsigned short Wl[256 * 72];
    __shared__ unsigned short TS[5120];
    __shared__ float ab2_s[128];
    unsigned short* Tt = TS;
    unsigned short* St = TS + 2560;
    unsigned short* Yt = TS;

    for (int j = wv; j < 36; j += 4) {
        const unsigned short* gp = wzb + j * 512 + ln * 8;
        __builtin_amdgcn_global_load_lds(
            (const __attribute__((address_space(1))) unsigned int*)gp,
            (__attribute__((address_space(3))) unsigned int*)&Wl[j * 512],
            16, 0, 0);
    }
    if (tid < 64) {
        const float inv = 1.0f / (BB * HWN);
        float mean = bn2acc[tid] * inv;
        float var  = bn2acc[64 + tid] * inv - mean * mean;
        float a = gamma[tid] * rsqrtf(var + 1e-5f);
        ab2_s[tid] = a;
        ab2_s[64 + tid] = beta[tid] - mean * a;
    }
    {
        const unsigned int* sgw = (const unsigned int*)(Sg + (size_t)b * 2560);
        unsigned int* stw = (unsigned int*)St;
        for (int i = tid; i < 1280; i += 256) stw[i] = sgw[i];
    }
    stage_Tt(Tt, th, b, hw0, tid);
    __syncthreads();

    short8 afy = *(const short8*)&Tt[(wv * 16 + col) * 40 + quad * 8];
    floatx4 yacc[4];
    #pragma unroll
    for (int nt = 0; nt < 4; ++nt) {
        short8 bf = *(const short8*)&St[(nt * 16 + col) * 40 + quad * 8];
        floatx4 z = (floatx4){0.f, 0.f, 0.f, 0.f};
        yacc[nt] = __builtin_amdgcn_mfma_f32_16x16x32_bf16(afy, bf, z, 0, 0, 0);
    }
    __syncthreads();

    #pragma unroll
    for (int nt = 0; nt < 4; ++nt) {
        int cg = nt * 16 + col;
        float a = ab2_s[cg], d = ab2_s[64 + cg];
        #pragma unroll
        for (int r = 0; r < 4; ++r) {
            int hwl = wv * 16 + quad * 4 + r;
            Yt[hwl * 72 + cg] = f2bf(fmaxf(fmaf(a, yacc[nt][r], d), 0.f));
        }
    }
    __syncthreads();

    floatx4 acc[16];
    #pragma unroll
    for (int nt = 0; nt < 16; ++nt) acc[nt] = (floatx4){0.f, 0.f, 0.f, 0.f};

    #pragma unroll
    for (int kk = 0; kk < 2; ++kk) {
        short8 afm = *(const short8*)&Yt[(wv * 16 + col) * 72 + kk * 32 + quad * 8];
        #pragma unroll
        for (int nt = 0; nt < 16; ++nt) {
            short8 bf = *(const short8*)&Wl[(nt * 16 + col) * 72 + kk * 32 + quad * 8];
            acc[nt] = __builtin_amdgcn_mfma_f32_16x16x32_bf16(afm, bf, acc[nt], 0, 0, 0);
        }
    }

    #pragma unroll
    for (int nt = 0; nt < 16; ++nt) {
        int co = nt * 16 + col;
        size_t base = ((size_t)(b * CC + co)) * HWN + hw0 + wv * 16 + quad * 4;
        float4 xv = *(const float4*)&x[base];
        float bz = b_z[co];
        float4 r = make_float4(acc[nt][0] + bz + xv.x, acc[nt][1] + bz + xv.y,
                               acc[nt][2] + bz + xv.z, acc[nt][3] + bz + xv.w);
        *(float4*)&out[base] = r;
    }
}

extern "C" void kernel_launch(void* const* d_in, const int* in_sizes, int n_in,
                              void* d_out, int out_size, void* d_ws, size_t ws_size,
                              hipStream_t stream) {
    (void)in_sizes; (void)n_in; (void)out_size; (void)ws_size;
    const float* x   = (const float*)d_in[0];
    const float* g1  = (const float*)d_in[1];
    const float* b1  = (const float*)d_in[2];
    const float* w_g = (const float*)d_in[3];
    const float* b_g = (const float*)d_in[4];
    const float* w_t = (const float*)d_in[5];
    const float* b_t = (const float*)d_in[6];
    const float* w_p = (const float*)d_in[7];
    const float* b_p = (const float*)d_in[8];
    const float* g2  = (const float*)d_in[9];
    const float* b2  = (const float*)d_in[10];
    const float* w_z = (const float*)d_in[11];
    const float* b_z = (const float*)d_in[12];
    float* out = (float*)d_out;

    float* ws      = (float*)d_ws;
    float* bn1part = ws;                                      // 8192
    float* zacc    = ws + 8192;                               // 17024
    float* bn2acc  = ws + 8192;                               // 128
    float* T1g     = ws + 8320;                               // 512
    float* Gg      = ws + 8832;                               // 16*1024
    unsigned short* wcat = (unsigned short*)(ws + 25216);
    unsigned short* wzb  = (unsigned short*)(ws + 41600);
    unsigned short* th   = (unsigned short*)(ws + 50816);
    unsigned short* pool = (unsigned short*)(ws + 853632);
    unsigned short* Sg   = (unsigned short*)(ws + 1468032);

    void* args[] = { &x, &g1, &b1, &w_g, &b_g, &w_t, &b_t, &w_p, &b_p, &g2, &b2, &w_z, &b_z,
                     &out, &wcat, &wzb, &th, &pool, &Sg, &bn1part, &zacc, &bn2acc, &T1g, &Gg };
    hipError_t err = hipLaunchCooperativeKernel((void*)k_fused, dim3(GRID), dim3(256),
                                                args, 0u, stream);
    if (err != hipSuccess) {
        // full known-passing R1 pipeline as backstop
        kf_head  <<<dim3(4224),    dim3(256), 0, stream>>>(x, w_t, w_p, w_g, w_z, wcat, wzb, pool, zacc, bn1part);
        kf_conv1 <<<dim3(28, BB),  dim3(256), 0, stream>>>(x, wcat, bn1part, g1, b1, b_g, b_t, b_p, th, pool, T1g, Gg);
        kf_sgemm <<<dim3(BB),      dim3(512), 0, stream>>>(pool, T1g, Gg, Sg, bn2acc);
        kf_convz <<<dim3(49, BB),  dim3(256), 0, stream>>>(th, Sg, wzb, bn2acc, g2, b2, b_z, x, out);
    }
}

// Round 5
// 170.136 us; speedup vs baseline: 2.4465x; 2.4465x over previous
//
#include <hip/hip_runtime.h>
#include <hip/hip_bf16.h>

#define BB 16
#define CC 256
#define HWN 3136
#define NCI 32
#define NPP 784   // 28*28

typedef __attribute__((ext_vector_type(8))) short short8;
typedef __attribute__((ext_vector_type(4))) float floatx4;

__device__ __forceinline__ unsigned short f2bf(float f) {
    union { __hip_bfloat16 h; unsigned short u; } cv;
    cv.h = __float2bfloat16(f);
    return cv.u;
}
__device__ __forceinline__ float bf2f(unsigned short u) {
    return __uint_as_float(((unsigned)u) << 16);
}

__device__ __forceinline__ void stage_Tt(unsigned short* Tt, const unsigned short* th,
                                         int b, int hw0, int tid) {
    int p2 = tid & 15, hwq = tid >> 4;
    int c0 = 2 * p2;
    const unsigned short* tb = th + (size_t)(b * NCI) * HWN + hw0 + hwq * 4;
    ushort4 v0 = *(const ushort4*)(tb + (size_t)c0 * HWN);
    ushort4 v1 = *(const ushort4*)(tb + (size_t)(c0 + 1) * HWN);
    unsigned int* tw = (unsigned int*)Tt;
    tw[(hwq * 4 + 0) * 20 + p2] = (unsigned)v0.x | ((unsigned)v1.x << 16);
    tw[(hwq * 4 + 1) * 20 + p2] = (unsigned)v0.y | ((unsigned)v1.y << 16);
    tw[(hwq * 4 + 2) * 20 + p2] = (unsigned)v0.z | ((unsigned)v1.z << 16);
    tw[(hwq * 4 + 3) * 20 + p2] = (unsigned)v0.w | ((unsigned)v1.w << 16);
}

// ---------------- kernel H: prep (blocks 0..127) + BN1 partial stats (blocks 128..4223) ----------------
__global__ __launch_bounds__(256) void k_head(const float* __restrict__ x,
                                              const float* __restrict__ w_t,
                                              const float* __restrict__ w_p,
                                              const float* __restrict__ w_g,
                                              const float* __restrict__ w_z,
                                              unsigned short* __restrict__ wcat,
                                              unsigned short* __restrict__ wzb,
                                              unsigned short* __restrict__ pool,
                                              float* __restrict__ zacc,
                                              float* __restrict__ bn1part) {
    int blk = blockIdx.x;
    int c = threadIdx.x;
    if (blk < 128) {
        int o = blk;
        const float* src = (o < 32) ? (w_t + o * CC)
                          : (o < 64) ? (w_p + (o - 32) * CC)
                                     : (w_g + (o - 64) * CC);
        wcat[o * CC + c] = f2bf(src[c]);
        {
            int r = o * 2 + (c >> 7);
            int kk = c & 127;
            if (kk < 72)
                wzb[r * 72 + kk] = (kk < 64) ? f2bf(w_z[r * 64 + kk]) : (unsigned short)0;
        }
        if (o < 96) {
            int b = c >> 4, kk = c & 15;
            pool[((size_t)(b * 96 + o)) * 800 + 784 + kk] = 0;
        }
        int idx = o * 256 + c;
        if (idx < 17024) zacc[idx] = 0.f;
        return;
    }
    int bc = blk - 128;
    const float4* p = (const float4*)(x + (size_t)bc * HWN);
    int tid = c;
    float s = 0.f, q = 0.f;
    for (int i = tid; i < 784; i += 256) {
        float4 v = p[i];
        s += v.x + v.y + v.z + v.w;
        q += v.x * v.x + v.y * v.y + v.z * v.z + v.w * v.w;
    }
    #pragma unroll
    for (int off = 32; off > 0; off >>= 1) {
        s += __shfl_down(s, off);
        q += __shfl_down(q, off);
    }
    __shared__ float sh[16];
    int wid = tid >> 6, lane = tid & 63;
    if (lane == 0) { sh[wid] = s; sh[8 + wid] = q; }
    __syncthreads();
    if (tid == 0) bn1part[bc]        = sh[0] + sh[1] + sh[2] + sh[3];
    if (tid == 1) bn1part[4096 + bc] = sh[8] + sh[9] + sh[10] + sh[11];
}

// ---------------- kernel 1: BN1+ReLU+conv1x1 MFMA + maxpool + T1 + Gram (512 thr, 8 waves) ----------------
// grid (28,B). M=128 o x N=112 hw; K=256. Each wave owns a 16-row M-band (acc[7]).
__global__ __launch_bounds__(512) void k_conv1(const float* __restrict__ x,
                                               const unsigned short* __restrict__ wcat,
                                               const float* __restrict__ bn1part,
                                               const float* __restrict__ gamma,
                                               const float* __restrict__ beta,
                                               const float* __restrict__ b_g,
                                               const float* __restrict__ b_t,
                                               const float* __restrict__ b_p,
                                               unsigned short* __restrict__ th,
                                               unsigned short* __restrict__ pool,
                                               float* __restrict__ T1g,
                                               float* __restrict__ Gg) {
    int b  = blockIdx.y;
    int bx = blockIdx.x;           // 0..27
    int hw0 = bx * 112;
    int tid = threadIdx.x;
    int wv = tid >> 6, ln = tid & 63;
    int col = ln & 15, quad = ln >> 4;

    __shared__ unsigned short smem[128 * 120];   // As[128*32] | Bs[112*32] during K-loop; Ct after
    unsigned short* As = smem;
    unsigned short* Bs = smem + 4096;
    __shared__ float ab_s[512];
    __shared__ float bias_s[128];

    if (tid < 256) {   // fold BN1 finalize from per-batch partials
        const float inv = 1.0f / (BB * HWN);
        float s = 0.f, q = 0.f;
        #pragma unroll
        for (int b2 = 0; b2 < BB; ++b2) {
            s += bn1part[b2 * 256 + tid];
            q += bn1part[4096 + b2 * 256 + tid];
        }
        float mean = s * inv;
        float var  = q * inv - mean * mean;
        float a = gamma[tid] * rsqrtf(var + 1e-5f);
        ab_s[tid] = a;
        ab_s[CC + tid] = beta[tid] - mean * a;
    }
    if (tid < 128) {
        int o = tid;
        bias_s[o] = (o < 32) ? b_t[o] : (o < 64) ? b_p[o - 32] : b_g[o - 64];
    }
    __syncthreads();

    floatx4 acc[7];
    #pragma unroll
    for (int nt = 0; nt < 7; ++nt)
        acc[nt] = (floatx4){0.f, 0.f, 0.f, 0.f};

    int p   = tid & 15;    // c-pair index
    int hwq = tid >> 4;    // hw-quad (0..31; active <28)
    bool act = hwq < 28;
    const float* xb = x + (size_t)(b * CC) * HWN + hw0;

    // prefetch k0=0
    float4 pv0, pv1;
    if (act) {
        int c0 = 2 * p;
        pv0 = *(const float4*)(xb + (size_t)c0 * HWN + hwq * 4);
        pv1 = *(const float4*)(xb + (size_t)(c0 + 1) * HWN + hwq * 4);
    }

    for (int k0 = 0; k0 < CC; k0 += 32) {
        {   // stage A (weights) via async DMA: wave wv covers rows 16wv..16wv+15
            const unsigned short* gp = wcat + (wv * 16 + (ln >> 2)) * CC + k0 + (ln & 3) * 8;
            __builtin_amdgcn_global_load_lds(
                (const __attribute__((address_space(1))) unsigned int*)gp,
                (__attribute__((address_space(3))) unsigned int*)&As[wv * 512],
                16, 0, 0);
        }
        if (act) {   // stage B from prefetched regs (BN1+ReLU+bf16)
            int c0 = k0 + 2 * p;
            float a0 = ab_s[c0],     d0 = ab_s[CC + c0];
            float a1 = ab_s[c0 + 1], d1 = ab_s[CC + c0 + 1];
            unsigned int* bw = (unsigned int*)Bs;
            float r0[4] = { fmaxf(fmaf(a0, pv0.x, d0), 0.f), fmaxf(fmaf(a0, pv0.y, d0), 0.f),
                            fmaxf(fmaf(a0, pv0.z, d0), 0.f), fmaxf(fmaf(a0, pv0.w, d0), 0.f) };
            float r1[4] = { fmaxf(fmaf(a1, pv1.x, d1), 0.f), fmaxf(fmaf(a1, pv1.y, d1), 0.f),
                            fmaxf(fmaf(a1, pv1.z, d1), 0.f), fmaxf(fmaf(a1, pv1.w, d1), 0.f) };
            #pragma unroll
            for (int i = 0; i < 4; ++i) {
                unsigned int w = (unsigned int)f2bf(r0[i]) | ((unsigned int)f2bf(r1[i]) << 16);
                bw[(hwq * 4 + i) * 16 + p] = w;
            }
        }
        __syncthreads();

        if (act && k0 + 32 < CC) {   // prefetch next k-step under the MFMAs
            int c0 = k0 + 32 + 2 * p;
            pv0 = *(const float4*)(xb + (size_t)c0 * HWN + hwq * 4);
            pv1 = *(const float4*)(xb + (size_t)(c0 + 1) * HWN + hwq * 4);
        }

        short8 af = *(const short8*)&As[(wv * 16 + col) * 32 + quad * 8];
        #pragma unroll
        for (int nt = 0; nt < 7; ++nt) {
            short8 bf = *(const short8*)&Bs[(nt * 16 + col) * 32 + quad * 8];
            acc[nt] = __builtin_amdgcn_mfma_f32_16x16x32_bf16(af, bf, acc[nt], 0, 0, 0);
        }
        __syncthreads();
    }

    // ---- stage C (with bias) to LDS ----
    unsigned short* Ct = smem;    // [128][120]
    {
        int obase = wv * 16 + quad * 4;
        #pragma unroll
        for (int r = 0; r < 4; ++r) {
            float bias = bias_s[obase + r];
            #pragma unroll
            for (int nt = 0; nt < 7; ++nt)
                Ct[(obase + r) * 120 + nt * 16 + col] = f2bf(acc[nt][r] + bias);
        }
    }
    __syncthreads();

    // ---- theta (ch 0..31): full-res vectorized store ----
    #pragma unroll
    for (int i = 0; i < 2; ++i) {
        int e = tid + i * 512;     // 896 = 32ch x 28 col4
        if (e < 896) {
            int ch = e / 28, c4 = e - ch * 28;
            ushort4 v = *(const ushort4*)&Ct[ch * 120 + c4 * 4];
            *(ushort4*)&th[((size_t)(b * NCI + ch)) * HWN + hw0 + c4 * 4] = v;
        }
    }
    // ---- T1: per-batch theta row sums (32 rows x 16 segs of 7) ----
    {
        int row = tid >> 4;      // 0..31
        int seg = tid & 15;      // 0..15
        float s = 0.f;
        #pragma unroll
        for (int j = 0; j < 7; ++j) s += bf2f(Ct[row * 120 + seg * 7 + j]);
        s += __shfl_down(s, 8);
        s += __shfl_down(s, 4);
        s += __shfl_down(s, 2);
        s += __shfl_down(s, 1);
        if (seg == 0) atomicAdd(&T1g[b * NCI + row], s);
    }
    // ---- Gram: theta.theta^T over this tile's 112 hw; 8 waves = 2x2 quadrants x 2 K-halves ----
    {
        int m = (wv >> 1) & 1, n = wv & 1;
        int ks0 = (wv >> 2) * 2;
        floatx4 g = (floatx4){0.f, 0.f, 0.f, 0.f};
        short8 z8 = (short8){0, 0, 0, 0, 0, 0, 0, 0};
        #pragma unroll
        for (int kx = 0; kx < 2; ++kx) {
            int ks = ks0 + kx;
            short8 ga, gb;
            if (ks < 3 || quad < 2) {   // k = ks*32 + quad*8 .. +7 must be < 112
                ga = *(const short8*)&Ct[(m * 16 + col) * 120 + ks * 32 + quad * 8];
                gb = *(const short8*)&Ct[(n * 16 + col) * 120 + ks * 32 + quad * 8];
            } else {
                ga = z8; gb = z8;
            }
            g = __builtin_amdgcn_mfma_f32_16x16x32_bf16(ga, gb, g, 0, 0, 0);
        }
        float* ggp = Gg + b * 1024 + (m * 16 + quad * 4) * 32 + n * 16 + col;
        #pragma unroll
        for (int r = 0; r < 4; ++r) atomicAdd(&ggp[r * 32], g[r]);
    }
    // ---- phi/g (ch 32..127): 2x2 maxpool ----
    #pragma unroll
    for (int i = 0; i < 6; ++i) {
        int e = tid + i * 512;     // 2688 = 96ch x 28 m
        if (e < 2688) {
            int ch = e / 28, m = e - ch * 28;
            const unsigned short* r0p = &Ct[(32 + ch) * 120 + 2 * m];
            float v = fmaxf(fmaxf(bf2f(r0p[0]), bf2f(r0p[1])),
                            fmaxf(bf2f(r0p[56]), bf2f(r0p[57])));
            pool[((size_t)(b * 96 + ch)) * 800 + bx * 28 + m] = f2bf(v);
        }
    }
}

// ---------------- kernel 3: S = g.phi^T/Np, cg-quartered (grid 4x16) + BN2 stats ----------------
// block (q,b): rows cg in [16q,16q+16), all 32 ci, K=800. 256 thr = 4 waves (K-split).
__global__ __launch_bounds__(256) void k_sgemm(const unsigned short* __restrict__ pool,
                                               const float* __restrict__ T1g,
                                               const float* __restrict__ Gg,
                                               unsigned short* __restrict__ Sg,
                                               float* __restrict__ bn2acc) {
    int q = blockIdx.x;            // 0..3  cg quarter
    int b = blockIdx.y;
    int tid = threadIdx.x;
    int wv = tid >> 6, ln = tid & 63;
    int col = ln & 15, quad = ln >> 4;
    __shared__ float Sred[4 * 512];
    __shared__ float Gred[1024];
    __shared__ float T1s[32];
    __shared__ float shs[16], shq[16];

    if (tid < 16) { shs[tid] = 0.f; shq[tid] = 0.f; }
    if (tid < 32) T1s[tid] = T1g[b * NCI + tid];
    for (int idx = tid; idx < 1024; idx += 256) Gred[idx] = Gg[b * 1024 + idx];

    const unsigned short* gbase = pool + ((size_t)(b * 96 + 32 + q * 16)) * 800;  // 16 g rows
    const unsigned short* pbase = pool + ((size_t)(b * 96)) * 800;                // phi rows
    floatx4 acc[2];
    acc[0] = (floatx4){0.f, 0.f, 0.f, 0.f};
    acc[1] = (floatx4){0.f, 0.f, 0.f, 0.f};
    for (int ks = wv; ks < 25; ks += 4) {
        int k0 = ks * 32;
        short8 af = *(const short8*)&gbase[(size_t)col * 800 + k0 + quad * 8];
        #pragma unroll
        for (int nt = 0; nt < 2; ++nt) {
            short8 bf = *(const short8*)&pbase[(nt * 16 + col) * 800 + k0 + quad * 8];
            acc[nt] = __builtin_amdgcn_mfma_f32_16x16x32_bf16(af, bf, acc[nt], 0, 0, 0);
        }
    }
    #pragma unroll
    for (int nt = 0; nt < 2; ++nt)
        for (int r = 0; r < 4; ++r)
            Sred[wv * 512 + (quad * 4 + r) * 32 + nt * 16 + col] = acc[nt][r];
    __syncthreads();

    // reduce 4 K-slices -> Sg global (bf16, pre-scaled) + Sred[0..511] (bf16-rounded f32)
    for (int idx = tid; idx < 512; idx += 256) {
        float s = Sred[idx] + Sred[512 + idx] + Sred[1024 + idx] + Sred[1536 + idx];
        int cgl = idx >> 5, ci = idx & 31;
        unsigned short h = f2bf(s * (1.0f / NPP));
        Sg[(size_t)b * 2560 + (q * 16 + cgl) * 40 + ci] = h;
        Sred[idx] = bf2f(h);
    }
    __syncthreads();

    {   // BN2 stats for this block's 16 cg rows: sum = S.T1, sumsq = s^T G s
        int cgl = tid & 15, part = tid >> 4;   // 16 parts x 2 ci
        float sum = 0.f, sq = 0.f;
        #pragma unroll
        for (int i = 0; i < 2; ++i) {
            int ci = part * 2 + i;
            float sv = Sred[cgl * 32 + ci];
            sum += sv * T1s[ci];
            float t2 = 0.f;
            #pragma unroll
            for (int cj = 0; cj < 32; ++cj)
                t2 += Gred[ci * 32 + cj] * Sred[cgl * 32 + cj];
            sq += sv * t2;
        }
        atomicAdd(&shs[cgl], sum);
        atomicAdd(&shq[cgl], sq);
    }
    __syncthreads();
    if (tid < 16) {
        atomicAdd(&bn2acc[q * 16 + tid], shs[tid]);
        atomicAdd(&bn2acc[64 + q * 16 + tid], shq[tid]);
    }
}

// ---------------- kernel 4: recompute y-tile + BN2+ReLU + conv1x1(z) + residual ----------------
__global__ __launch_bounds__(256) void k_convz(const unsigned short* __restrict__ th,
                                               const unsigned short* __restrict__ Sg,
                                               const unsigned short* __restrict__ wzb,
                                               const float* __restrict__ bn2acc,
                                               const float* __restrict__ gamma,
                                               const float* __restrict__ beta,
                                               const float* __restrict__ b_z,
                                               const float* __restrict__ x,
                                               float* __restrict__ out) {
    int b = blockIdx.y;
    int hw0 = blockIdx.x * 64;
    int tid = threadIdx.x;
    int wv = tid >> 6, ln = tid & 63;
    int col = ln & 15, quad = ln >> 4;

    __shared__ unsigned short Wl[256 * 72];
    __shared__ unsigned short TS[5120];
    __shared__ float ab2_s[128];
    unsigned short* Tt = TS;
    unsigned short* St = TS + 2560;
    unsigned short* Yt = TS;

    for (int j = wv; j < 36; j += 4) {
        const unsigned short* gp = wzb + j * 512 + ln * 8;
        __builtin_amdgcn_global_load_lds(
            (const __attribute__((address_space(1))) unsigned int*)gp,
            (__attribute__((address_space(3))) unsigned int*)&Wl[j * 512],
            16, 0, 0);
    }
    if (tid < 64) {
        const float inv = 1.0f / (BB * HWN);
        float mean = bn2acc[tid] * inv;
        float var  = bn2acc[64 + tid] * inv - mean * mean;
        float a = gamma[tid] * rsqrtf(var + 1e-5f);
        ab2_s[tid] = a;
        ab2_s[64 + tid] = beta[tid] - mean * a;
    }
    {
        const unsigned int* sgw = (const unsigned int*)(Sg + (size_t)b * 2560);
        unsigned int* stw = (unsigned int*)St;
        for (int i = tid; i < 1280; i += 256) stw[i] = sgw[i];
    }
    stage_Tt(Tt, th, b, hw0, tid);
    __syncthreads();

    short8 afy = *(const short8*)&Tt[(wv * 16 + col) * 40 + quad * 8];
    floatx4 yacc[4];
    #pragma unroll
    for (int nt = 0; nt < 4; ++nt) {
        short8 bf = *(const short8*)&St[(nt * 16 + col) * 40 + quad * 8];
        floatx4 z = (floatx4){0.f, 0.f, 0.f, 0.f};
        yacc[nt] = __builtin_amdgcn_mfma_f32_16x16x32_bf16(afy, bf, z, 0, 0, 0);
    }
    __syncthreads();

    #pragma unroll
    for (int nt = 0; nt < 4; ++nt) {
        int cg = nt * 16 + col;
        float a = ab2_s[cg], d = ab2_s[64 + cg];
        #pragma unroll
        for (int r = 0; r < 4; ++r) {
            int hwl = wv * 16 + quad * 4 + r;
            Yt[hwl * 72 + cg] = f2bf(fmaxf(fmaf(a, yacc[nt][r], d), 0.f));
        }
    }
    __syncthreads();

    floatx4 acc[16];
    #pragma unroll
    for (int nt = 0; nt < 16; ++nt) acc[nt] = (floatx4){0.f, 0.f, 0.f, 0.f};

    #pragma unroll
    for (int kk = 0; kk < 2; ++kk) {
        short8 afm = *(const short8*)&Yt[(wv * 16 + col) * 72 + kk * 32 + quad * 8];
        #pragma unroll
        for (int nt = 0; nt < 16; ++nt) {
            short8 bf = *(const short8*)&Wl[(nt * 16 + col) * 72 + kk * 32 + quad * 8];
            acc[nt] = __builtin_amdgcn_mfma_f32_16x16x32_bf16(afm, bf, acc[nt], 0, 0, 0);
        }
    }

    #pragma unroll
    for (int nt = 0; nt < 16; ++nt) {
        int co = nt * 16 + col;
        size_t base = ((size_t)(b * CC + co)) * HWN + hw0 + wv * 16 + quad * 4;
        float4 xv = *(const float4*)&x[base];
        float bz = b_z[co];
        float4 r = make_float4(acc[nt][0] + bz + xv.x, acc[nt][1] + bz + xv.y,
                               acc[nt][2] + bz + xv.z, acc[nt][3] + bz + xv.w);
        *(float4*)&out[base] = r;
    }
}

extern "C" void kernel_launch(void* const* d_in, const int* in_sizes, int n_in,
                              void* d_out, int out_size, void* d_ws, size_t ws_size,
                              hipStream_t stream) {
    (void)in_sizes; (void)n_in; (void)out_size; (void)ws_size;
    const float* x   = (const float*)d_in[0];
    const float* g1  = (const float*)d_in[1];
    const float* b1  = (const float*)d_in[2];
    const float* w_g = (const float*)d_in[3];
    const float* b_g = (const float*)d_in[4];
    const float* w_t = (const float*)d_in[5];
    const float* b_t = (const float*)d_in[6];
    const float* w_p = (const float*)d_in[7];
    const float* b_p = (const float*)d_in[8];
    const float* g2  = (const float*)d_in[9];
    const float* b2  = (const float*)d_in[10];
    const float* w_z = (const float*)d_in[11];
    const float* b_z = (const float*)d_in[12];
    float* out = (float*)d_out;

    float* ws      = (float*)d_ws;
    float* bn1part = ws;                                      // 8192
    float* zacc    = ws + 8192;                               // bn2acc(128)+T1g(512)+Gg(16384)
    float* bn2acc  = ws + 8192;                               // 128
    float* T1g     = ws + 8320;                               // 512
    float* Gg      = ws + 8832;                               // 16*1024
    unsigned short* wcat = (unsigned short*)(ws + 25216);
    unsigned short* wzb  = (unsigned short*)(ws + 41600);
    unsigned short* th   = (unsigned short*)(ws + 50816);
    unsigned short* pool = (unsigned short*)(ws + 853632);
    unsigned short* Sg   = (unsigned short*)(ws + 1468032);

    k_head  <<<dim3(4224),     dim3(256), 0, stream>>>(x, w_t, w_p, w_g, w_z, wcat, wzb, pool, zacc, bn1part);
    k_conv1 <<<dim3(28, BB),   dim3(512), 0, stream>>>(x, wcat, bn1part, g1, b1, b_g, b_t, b_p, th, pool, T1g, Gg);
    k_sgemm <<<dim3(4, BB),    dim3(256), 0, stream>>>(pool, T1g, Gg, Sg, bn2acc);
    k_convz <<<dim3(49, BB),   dim3(256), 0, stream>>>(th, Sg, wzb, bn2acc, g2, b2, b_z, x, out);
}